// Round 11
// baseline (243.678 us; speedup 1.0000x reference)
//
#include <hip/hip_runtime.h>
#include <math.h>

#define HH 512
#define FF 2048
#define BB 16
#define SS 2048
#define MM 32768  // BB*SS

using f32x4 = __attribute__((ext_vector_type(4))) float;
using s16x8 = __attribute__((ext_vector_type(8))) short;

struct __align__(8)  US4 { unsigned short x, y, z, w; };
struct __align__(16) US8 { unsigned short s[8]; };

__device__ __forceinline__ unsigned short f2bf(float f) {
  unsigned int u = __builtin_bit_cast(unsigned int, f);
  u += 0x7fffu + ((u >> 16) & 1u);
  return (unsigned short)(u >> 16);
}
__device__ __forceinline__ float bf2f(unsigned short u) {
  unsigned int x = ((unsigned int)u) << 16;
  return __builtin_bit_cast(float, x);
}

// ---- weight conversions (merged) ----
__global__ void k_conv(const float* __restrict__ We, const float* __restrict__ Wa,
                       unsigned short* __restrict__ OWe, unsigned short* __restrict__ OWa) {
  int bid = blockIdx.x, t = threadIdx.x;
  if (bid < 1024) {
    int idx = bid * 256 + t;  // < 262144
    f32x4 x = *(const f32x4*)(We + (size_t)idx * 4);
    US4 p{f2bf(x.x), f2bf(x.y), f2bf(x.z), f2bf(x.w)};
    *(US4*)(OWe + (size_t)idx * 4) = p;
  } else {
    int idx = (bid - 1024) * 256 + t;  // < 65536
    int k = idx >> 7, h4 = idx & 127;
    f32x4 x = *(const f32x4*)(Wa + (size_t)k * 1024 + 512 + h4 * 4);
    US4 p{f2bf(x.x), f2bf(x.y), f2bf(x.z), f2bf(x.w)};
    *(US4*)(OWa + (size_t)idx * 4) = p;
  }
}

// ---- h = hidden[-1] @ Wh.T + bh ----
__global__ void k_h(const float* __restrict__ hidden, const float* __restrict__ Wh,
                    const float* __restrict__ bh, float* __restrict__ h_ws) {
  int t = threadIdx.x, lane = t & 63, wid = t >> 6;
  int out = blockIdx.x * 4 + wid;  // < 8192
  int b = out >> 9, j = out & 511;
  const float* hr = hidden + (1) * BB * FF + b * FF;
  const float* wr = Wh + (size_t)j * FF;
  float a = 0.f;
#pragma unroll
  for (int i = 0; i < 8; ++i) {
    int o = i * 256 + lane * 4;
    f32x4 x = *(const f32x4*)(hr + o);
    f32x4 y = *(const f32x4*)(wr + o);
    a += x.x * y.x + x.y * y.y + x.z * y.z + x.w * y.w;
  }
#pragma unroll
  for (int m = 32; m; m >>= 1) a += __shfl_xor(a, m);
  if (lane == 0) h_ws[out] = a + bh[j];
}

// ---- bb[b][k] = ba[k] + h[b] . Wa[k, 0:512] ----
__global__ void k_bb(const float* __restrict__ h_ws, const float* __restrict__ Wa,
                     const float* __restrict__ ba, float* __restrict__ bb_ws) {
  int t = threadIdx.x, lane = t & 63, wid = t >> 6;
  int out = blockIdx.x * 4 + wid;  // < 8192
  int b = out >> 9, k = out & 511;
  const float* hr = h_ws + b * HH;
  const float* wa = Wa + (size_t)k * 1024;
  float a = 0.f;
#pragma unroll
  for (int i = 0; i < 2; ++i) {
    int o = i * 256 + lane * 4;
    f32x4 x = *(const f32x4*)(hr + o);
    f32x4 y = *(const f32x4*)(wa + o);
    a += x.x * y.x + x.y * y.y + x.z * y.z + x.w * y.w;
  }
#pragma unroll
  for (int m = 32; m; m >>= 1) a += __shfl_xor(a, m);
  if (lane == 0) bb_ws[out] = a + ba[k];
}

// ====== fused GEMM1 + GEMM2 + scores: B-in-registers, A-only LDS ======
// Diagnosis R5-R10: B's gload_lds L2 round-trip is serialized inside every
// K-step (waited within the phase it's issued). Fix: B fragments load s16x8
// DIRECTLY from L2 into registers with half-step-ahead software prefetch
// (R8's addressing, which passed correctness, + the prefetch R8 lacked).
// A-tile (HBM f32->bf16, 8-wave reuse) stays in LDS: 2x8KB dbuf, 1-step reg
// prefetch, ONE raw s_barrier + lgkmcnt(0) per K-step. ZERO vm drains.
// LDS: As0@0 | As1@8K | Cs@16K (64KB epilogue) = 80KB => 2 blocks/CU.
// A-subtile layout (linear write, conflict-free 16-lane reads):
//   elem(row,k) at byte ((k>>3)*4 + row/16)*256 + (row%16)*16 + (k&7)*2.
__global__ __launch_bounds__(512, 4) void k_gemm1f(
    const float* __restrict__ enc, const unsigned short* __restrict__ Web,
    const float* __restrict__ be, const unsigned short* __restrict__ Waeb,
    const float* __restrict__ bbw, const float* __restrict__ vv,
    unsigned short* __restrict__ eo, float* __restrict__ sp) {
  __shared__ char smem[81920];  // 80 KB
  const int t = threadIdx.x, lane = t & 63, wid = t >> 6;
  const int m0 = blockIdx.x * 64;
  const float* enc_m0 = enc + (size_t)m0 * FF;
  f32x4 acc[4][4] = {};

  // A staging coords: thread t stages (row = t&63, k-octet = t>>6)
  const int sRow = t & 63;
  const int sKb  = t >> 6;
  const int sDst = ((sKb * 4 + (sRow >> 4)) << 8) + ((sRow & 15) << 4);
  const float* ap = enc_m0 + (size_t)sRow * FF + sKb * 8;

  // B fragment base: col = wid*64 + ni*16 + (lane&15), k-offset (lane>>4)*8
  const unsigned short* bp = Web + (size_t)(wid * 64 + (lane & 15)) * FF + ((lane >> 4) << 3);

  // ---- prologue: A(0)->As0; A(64)->regs; B(0,ks0)->bA ----
  f32x4 ar0, ar1;
  {
    f32x4 w0 = *(const f32x4*)ap;
    f32x4 w1 = *(const f32x4*)(ap + 4);
    US8 o{f2bf(w0.x), f2bf(w0.y), f2bf(w0.z), f2bf(w0.w),
          f2bf(w1.x), f2bf(w1.y), f2bf(w1.z), f2bf(w1.w)};
    *(US8*)(smem + sDst) = o;
    ar0 = *(const f32x4*)(ap + 64);
    ar1 = *(const f32x4*)(ap + 68);
  }
  s16x8 bA[4], bB[4];
#pragma unroll
  for (int ni = 0; ni < 4; ++ni)
    bA[ni] = *(const s16x8*)(bp + (size_t)ni * 16 * FF);
  asm volatile("s_waitcnt lgkmcnt(0)" ::: "memory");
  __builtin_amdgcn_s_barrier();
  __builtin_amdgcn_sched_barrier(0);

  // ---- main loop: 32 K-steps, 1 barrier each, no vm drains ----
#pragma unroll 1
  for (int kt = 0; kt < FF; kt += 64) {
    char* AsC = smem + (((kt >> 6) & 1) << 13);
    char* AsN = smem + ((((kt >> 6) & 1) ^ 1) << 13);
    // issue B(kt, ks1) early (covered by ks0 compute)
#pragma unroll
    for (int ni = 0; ni < 4; ++ni)
      bB[ni] = *(const s16x8*)(bp + (size_t)ni * 16 * FF + kt + 32);
    // publish A(kt+64) (loaded a full step ago); prefetch A(kt+128)
    if (kt < 1984) {
      US8 o{f2bf(ar0.x), f2bf(ar0.y), f2bf(ar0.z), f2bf(ar0.w),
            f2bf(ar1.x), f2bf(ar1.y), f2bf(ar1.z), f2bf(ar1.w)};
      *(US8*)(AsN + sDst) = o;
      if (kt < 1920) {
        ar0 = *(const f32x4*)(ap + kt + 128);
        ar1 = *(const f32x4*)(ap + kt + 132);
      }
    }
    // ks=0: af from LDS, MFMA with bA (in flight since last half-step)
    s16x8 af[4];
#pragma unroll
    for (int mi = 0; mi < 4; ++mi)
      af[mi] = *(const s16x8*)(AsC + (((lane >> 4)) * 4 + mi) * 256 + ((lane & 15) << 4));
#pragma unroll
    for (int mi = 0; mi < 4; ++mi)
#pragma unroll
      for (int ni = 0; ni < 4; ++ni)
        acc[mi][ni] = __builtin_amdgcn_mfma_f32_16x16x32_bf16(af[mi], bA[ni], acc[mi][ni], 0, 0, 0);
    // issue B(kt+64, ks0) (covered by ks1 compute + barrier)
    if (kt < 1984) {
#pragma unroll
      for (int ni = 0; ni < 4; ++ni)
        bA[ni] = *(const s16x8*)(bp + (size_t)ni * 16 * FF + kt + 64);
    }
    // ks=1: af from LDS, MFMA with bB
#pragma unroll
    for (int mi = 0; mi < 4; ++mi)
      af[mi] = *(const s16x8*)(AsC + ((4 + (lane >> 4)) * 4 + mi) * 256 + ((lane & 15) << 4));
#pragma unroll
    for (int mi = 0; mi < 4; ++mi)
#pragma unroll
      for (int ni = 0; ni < 4; ++ni)
        acc[mi][ni] = __builtin_amdgcn_mfma_f32_16x16x32_bf16(af[mi], bB[ni], acc[mi][ni], 0, 0, 0);
    // single barrier: LDS reads + publish retired; B/A global loads keep flying
    asm volatile("s_waitcnt lgkmcnt(0)" ::: "memory");
    __builtin_amdgcn_s_barrier();
    __builtin_amdgcn_sched_barrier(0);
  }

  // ---- epilogue 1: acc (+be) -> swizzled Cs @16KB ----
  unsigned short* Cs = (unsigned short*)(smem + 16384);  // [64][512] bf16, byte = r*1024 + ((c*2)^((r&7)<<4))
#pragma unroll
  for (int ni = 0; ni < 4; ++ni) {
    int col = wid * 64 + ni * 16 + (lane & 15);
    float bev = be[col];
#pragma unroll
    for (int mi = 0; mi < 4; ++mi)
#pragma unroll
      for (int j = 0; j < 4; ++j) {
        int row = mi * 16 + (lane >> 4) * 4 + j;
        int byte = row * 1024 + ((col * 2) ^ ((row & 7) << 4));
        *(unsigned short*)((char*)Cs + byte) = f2bf(acc[mi][ni][j] + bev);
      }
  }
  __syncthreads();

  // ---- epilogue 2: coalesced eo store (de-swizzled US8 reads) ----
#pragma unroll
  for (int i = 0; i < 8; ++i) {
    int idx = i * 512 + t, row = idx >> 6, c = idx & 63;
    int byte = row * 1024 + ((c * 16) ^ ((row & 7) << 4));
    *(US8*)(eo + (size_t)(m0 + row) * HH + c * 8) = *(const US8*)((const char*)Cs + byte);
  }

  // ---- epilogue 3: GEMM2  E(64x64 per wave) = eoTile @ Waeb^T (B from L2) ----
  f32x4 acc2[4][4] = {};
#pragma unroll
  for (int kt2 = 0; kt2 < HH; kt2 += 64) {
#pragma unroll
    for (int ks = 0; ks < 2; ++ks) {
      int k2 = kt2 + ks * 32 + (lane >> 4) * 8;
      s16x8 af[4], bfr[4];
#pragma unroll
      for (int mi = 0; mi < 4; ++mi) {
        int row = mi * 16 + (lane & 15);
        int byte = row * 1024 + ((k2 * 2) ^ ((row & 7) << 4));
        af[mi] = *(const s16x8*)((const char*)Cs + byte);
      }
#pragma unroll
      for (int ni = 0; ni < 4; ++ni) {
        int nrow = wid * 64 + ni * 16 + (lane & 15);
        bfr[ni] = *(const s16x8*)(Waeb + (size_t)nrow * HH + k2);
      }
#pragma unroll
      for (int mi = 0; mi < 4; ++mi)
#pragma unroll
        for (int ni = 0; ni < 4; ++ni)
          acc2[mi][ni] = __builtin_amdgcn_mfma_f32_16x16x32_bf16(af[mi], bfr[ni], acc2[mi][ni], 0, 0, 0);
    }
  }

  // ---- epilogue 4: scores = sum_n tanh(E + bb) * v ----
  const int b = m0 >> 11;
  float vcol[4], bcol[4];
#pragma unroll
  for (int ni = 0; ni < 4; ++ni) {
    int col = wid * 64 + ni * 16 + (lane & 15);
    vcol[ni] = vv[col];
    bcol[ni] = bbw[b * HH + col];
  }
  float ps[4][4];
#pragma unroll
  for (int mi = 0; mi < 4; ++mi)
#pragma unroll
    for (int j = 0; j < 4; ++j) {
      float s = 0.f;
#pragma unroll
      for (int ni = 0; ni < 4; ++ni)
        s += tanhf(acc2[mi][ni][j] + bcol[ni]) * vcol[ni];
      ps[mi][j] = s;
    }
#pragma unroll
  for (int m = 1; m < 16; m <<= 1)
#pragma unroll
    for (int mi = 0; mi < 4; ++mi)
#pragma unroll
      for (int j = 0; j < 4; ++j) ps[mi][j] += __shfl_xor(ps[mi][j], m);
  float* red = (float*)smem;  // 2KB @0 (As region dead; Cs untouched)
  if ((lane & 15) == 0) {
#pragma unroll
    for (int mi = 0; mi < 4; ++mi)
#pragma unroll
      for (int j = 0; j < 4; ++j)
        red[wid * 64 + mi * 16 + (lane >> 4) * 4 + j] = ps[mi][j];
  }
  __syncthreads();
  if (t < 64) {
    float s = 0.f;
#pragma unroll
    for (int w = 0; w < 8; ++w) s += red[w * 64 + t];
    sp[m0 + t] = s;
  }
}

// ---- softmax over S per batch ----
__global__ void k_softmax(const float* __restrict__ sp, float* __restrict__ attn) {
  const int b = blockIdx.x, t = threadIdx.x, lane = t & 63, wid = t >> 6;
  __shared__ float red[4];
  float vals[8], lmax = -3.0e38f;
#pragma unroll
  for (int i = 0; i < 8; ++i) {
    float x = sp[b * SS + t + i * 256];
    vals[i] = x;
    lmax = fmaxf(lmax, x);
  }
#pragma unroll
  for (int m = 32; m; m >>= 1) lmax = fmaxf(lmax, __shfl_xor(lmax, m));
  if (lane == 0) red[wid] = lmax;
  __syncthreads();
  lmax = fmaxf(fmaxf(red[0], red[1]), fmaxf(red[2], red[3]));
  __syncthreads();
  float lsum = 0.f;
#pragma unroll
  for (int i = 0; i < 8; ++i) {
    vals[i] = __expf(vals[i] - lmax);
    lsum += vals[i];
  }
#pragma unroll
  for (int m = 32; m; m >>= 1) lsum += __shfl_xor(lsum, m);
  if (lane == 0) red[wid] = lsum;
  __syncthreads();
  float inv = 1.0f / (red[0] + red[1] + red[2] + red[3]);
#pragma unroll
  for (int i = 0; i < 8; ++i) attn[b * SS + t + i * 256] = vals[i] * inv;
}

// ---- context stage 1 ----
__global__ __launch_bounds__(512) void k_ctx1(const unsigned short* __restrict__ eo,
                                              const float* __restrict__ attn,
                                              float* __restrict__ cp) {
  __shared__ float red[8][512];
  const int b = blockIdx.x >> 4, ch = blockIdx.x & 15, t = threadIdx.x;
  const int tg = t & 63, sg = t >> 6;
  const float* aw = attn + b * SS + ch * 128;
  float acc[8] = {};
#pragma unroll 4
  for (int i = 0; i < 16; ++i) {
    int s = sg + i * 8;
    float w = aw[s];
    US8 vv8 = *(const US8*)(eo + (size_t)(b * SS + ch * 128 + s) * HH + tg * 8);
#pragma unroll
    for (int j = 0; j < 8; ++j) acc[j] += w * bf2f(vv8.s[j]);
  }
#pragma unroll
  for (int j = 0; j < 8; ++j) red[sg][tg * 8 + j] = acc[j];
  __syncthreads();
  float a = 0.f;
#pragma unroll
  for (int g = 0; g < 8; ++g) a += red[g][t];
  cp[(size_t)blockIdx.x * HH + t] = a;
}

// ---- context stage 2 ----
__global__ void k_ctx2(const float* __restrict__ cp, float* __restrict__ ctx) {
  const int b = blockIdx.x, h = threadIdx.x;
  float a = 0.f;
#pragma unroll
  for (int c = 0; c < 16; ++c) a += cp[(size_t)(b * 16 + c) * HH + h];
  ctx[b * HH + h] = a;
}

extern "C" void kernel_launch(void* const* d_in, const int* in_sizes, int n_in,
                              void* d_out, int out_size, void* d_ws, size_t ws_size,
                              hipStream_t stream) {
  (void)in_sizes; (void)n_in; (void)out_size; (void)ws_size;
  const float* hidden = (const float*)d_in[0];
  const float* enc    = (const float*)d_in[1];
  const float* We     = (const float*)d_in[2];
  const float* be     = (const float*)d_in[3];
  const float* Wh     = (const float*)d_in[4];
  const float* bh     = (const float*)d_in[5];
  const float* Wa     = (const float*)d_in[6];
  const float* ba     = (const float*)d_in[7];
  const float* v      = (const float*)d_in[8];

  float* out  = (float*)d_out;
  float* ctx  = out;            // 16*512
  float* attn = out + BB * HH;  // 16*2048

  char* ws = (char*)d_ws;
  unsigned short* Web  = (unsigned short*)ws;  ws += (size_t)HH * FF * 2;     // 2 MB
  unsigned short* Waeb = (unsigned short*)ws;  ws += (size_t)HH * HH * 2;     // 512 KB
  float* h_ws  = (float*)ws;                   ws += (size_t)BB * HH * 4;     // 32 KB
  float* bb_ws = (float*)ws;                   ws += (size_t)BB * HH * 4;     // 32 KB
  unsigned short* eo = (unsigned short*)ws;    ws += (size_t)MM * HH * 2;     // 32 MB
  float* sp = (float*)ws;                      ws += (size_t)MM * 4;          // 128 KB
  float* cp = (float*)ws;                      ws += (size_t)BB * 16 * HH * 4;// 512 KB

  k_conv<<<1280, 256, 0, stream>>>(We, Wa, Web, Waeb);
  k_h<<<2048, 256, 0, stream>>>(hidden, Wh, bh, h_ws);
  k_bb<<<2048, 256, 0, stream>>>(h_ws, Wa, ba, bb_ws);
  k_gemm1f<<<512, 512, 0, stream>>>(enc, Web, be, Waeb, bb_ws, v, eo, sp);
  k_softmax<<<16, 256, 0, stream>>>(sp, attn);
  k_ctx1<<<256, 512, 0, stream>>>(eo, attn, cp);
  k_ctx2<<<16, 512, 0, stream>>>(cp, ctx);
}